// Round 2
// baseline (2247.168 us; speedup 1.0000x reference)
//
#include <hip/hip_runtime.h>
#include <hip/hip_bf16.h>

#define NN 50000
#define NE 800000
#define DD 64
#define NL 3

// ---------------------------------------------------------------------------
// Scatter: agg[dst[e]][:] += w[e] * h[src[e]][:]
// 16 threads per edge, float4 per thread (64 cols). Atomics into L2/L3-resident
// agg (12.8 MB). Contention low: ~16 edges/node over 3.2M distinct addresses.
// ---------------------------------------------------------------------------
__global__ void scatter_kernel(const float* __restrict__ h,
                               const int* __restrict__ src,
                               const int* __restrict__ dst,
                               const float* __restrict__ w,
                               float* __restrict__ agg) {
    int t = blockIdx.x * blockDim.x + threadIdx.x;
    int e = t >> 4;            // 16 threads per edge
    if (e >= NE) return;
    int c = (t & 15) << 2;     // 4 consecutive floats per thread
    int s = src[e];
    int d = dst[e];
    float we = w[e];
    const float4 hv = *reinterpret_cast<const float4*>(h + (size_t)s * DD + c);
    float* ap = agg + (size_t)d * DD + c;
    atomicAdd(ap + 0, we * hv.x);
    atomicAdd(ap + 1, we * hv.y);
    atomicAdd(ap + 2, we * hv.z);
    atomicAdd(ap + 3, we * hv.w);
}

// ---------------------------------------------------------------------------
// Dense update: out = agg @ Wrel + b + h @ Wroot   (+ tanh on last layer)
// Block = 256 threads, ROWS=16 rows per block. Both 64x64 W matrices staged in
// LDS (32 KB), plus the 16 agg rows + 16 h rows (8 KB). Inner loop: lane d
// reads sW[k][d] (stride-1 across lanes -> 2-way bank aliasing, free) and
// sAgg/sH[r][k] (wave broadcast, free).
// ---------------------------------------------------------------------------
template<bool LAST>
__global__ void update_kernel(const float* __restrict__ agg,
                              const float* __restrict__ h,
                              const float* __restrict__ Wrel,
                              const float* __restrict__ Wroot,
                              const float* __restrict__ b,
                              float* __restrict__ out) {
    constexpr int ROWS = 16;
    __shared__ float sWrel[DD][DD];
    __shared__ float sWroot[DD][DD];
    __shared__ float sAgg[ROWS][DD];
    __shared__ float sH[ROWS][DD];

    const int tid = threadIdx.x;
    // Stage W matrices (4096 floats each) as float4
    for (int i = tid; i < DD * DD / 4; i += blockDim.x) {
        reinterpret_cast<float4*>(&sWrel[0][0])[i]  = reinterpret_cast<const float4*>(Wrel)[i];
        reinterpret_cast<float4*>(&sWroot[0][0])[i] = reinterpret_cast<const float4*>(Wroot)[i];
    }
    const int row0 = blockIdx.x * ROWS;
    // Stage the block's agg/h rows as float4 (ROWS*16 = 256 float4 each)
    for (int i = tid; i < ROWS * DD / 4; i += blockDim.x) {
        int r = i >> 4;        // D/4 = 16 float4 per row
        int c = i & 15;
        int gr = row0 + r;
        if (gr < NN) {
            reinterpret_cast<float4*>(&sAgg[r][0])[c] =
                reinterpret_cast<const float4*>(agg + (size_t)gr * DD)[c];
            reinterpret_cast<float4*>(&sH[r][0])[c] =
                reinterpret_cast<const float4*>(h + (size_t)gr * DD)[c];
        }
    }
    __syncthreads();

    const int d  = tid & 63;
    const int rg = tid >> 6;        // 4 row-groups of 4 rows
    const float bias = b[d];
    #pragma unroll
    for (int rr = 0; rr < 4; ++rr) {
        int r  = rg * 4 + rr;
        int gr = row0 + r;
        if (gr >= NN) continue;
        float acc = bias;
        #pragma unroll
        for (int k = 0; k < DD; ++k) {
            acc += sAgg[r][k] * sWrel[k][d] + sH[r][k] * sWroot[k][d];
        }
        if (LAST) acc = tanhf(acc);
        out[(size_t)gr * DD + d] = acc;
    }
}

extern "C" void kernel_launch(void* const* d_in, const int* in_sizes, int n_in,
                              void* d_out, int out_size, void* d_ws, size_t ws_size,
                              hipStream_t stream) {
    const float* x     = (const float*)d_in[0];
    const int*   ei    = (const int*)d_in[1];
    const float* ew    = (const float*)d_in[2];
    const float* Wrel  = (const float*)d_in[3];
    const float* brel  = (const float*)d_in[4];
    const float* Wroot = (const float*)d_in[5];
    float* out = (float*)d_out;   // output is float32 (round-1 post-mortem)

    // Workspace: agg (12.8MB) + one f32 h intermediate buffer (12.8MB).
    // Layer outputs: l0 -> hA, l1 -> hB, l2 -> out (tanh).
    float* agg = (float*)d_ws;
    float* hA  = agg + (size_t)NN * DD;
    float* hB  = hA + (size_t)NN * DD;

    const int* src = ei;            // edge_index[0]
    const int* dst = ei + NE;       // edge_index[1]

    const float* hcur = x;

    const int scatter_blocks = (NE * 16 + 255) / 256;   // 50000
    const int update_blocks  = (NN + 15) / 16;          // 3125

    for (int l = 0; l < NL; ++l) {
        hipMemsetAsync(agg, 0, (size_t)NN * DD * sizeof(float), stream);
        scatter_kernel<<<scatter_blocks, 256, 0, stream>>>(hcur, src, dst, ew, agg);
        const float* Wr = Wrel  + (size_t)l * DD * DD;
        const float* Wo = Wroot + (size_t)l * DD * DD;
        const float* bb = brel  + (size_t)l * DD;
        if (l == NL - 1) {
            update_kernel<true><<<update_blocks, 256, 0, stream>>>(
                agg, hcur, Wr, Wo, bb, out);
        } else {
            float* hnext = (l == 0) ? hA : hB;
            update_kernel<false><<<update_blocks, 256, 0, stream>>>(
                agg, hcur, Wr, Wo, bb, hnext);
            hcur = hnext;
        }
    }
}

// Round 4
// 606.452 us; speedup vs baseline: 3.7054x; 3.7054x over previous
//
#include <hip/hip_runtime.h>
#include <hip/hip_bf16.h>

#define NN 50000
#define NE 800000
#define DD 64
#define NL 3

// ---------------------------------------------------------------------------
// CSR build, step 1: histogram of in-degrees. cursor[] doubles as deg[].
// ---------------------------------------------------------------------------
__global__ void hist_kernel(const int* __restrict__ dst, int* __restrict__ cursor) {
    int e = blockIdx.x * blockDim.x + threadIdx.x;
    if (e >= NE) return;
    atomicAdd(&cursor[dst[e]], 1);
}

// ---------------------------------------------------------------------------
// CSR build, step 2: single-block exclusive scan of deg (in cursor[]) ->
// row_start[], and reset cursor[] to the running positions (= row_start).
// 50000 elements, 1024 threads, ~49 chunks. Tiny (~10 us).
// ---------------------------------------------------------------------------
__global__ void scan_kernel(int* __restrict__ cursor, int* __restrict__ row_start) {
    __shared__ int buf[1024];
    __shared__ int s_carry;
    const int tid = threadIdx.x;
    if (tid == 0) s_carry = 0;
    __syncthreads();
    for (int base = 0; base < NN; base += 1024) {
        int idx = base + tid;
        int v = (idx < NN) ? cursor[idx] : 0;
        buf[tid] = v;
        __syncthreads();
        for (int off = 1; off < 1024; off <<= 1) {
            int t = (tid >= off) ? buf[tid - off] : 0;
            __syncthreads();
            buf[tid] += t;
            __syncthreads();
        }
        int excl = buf[tid] - v + s_carry;
        if (idx < NN) { row_start[idx] = excl; cursor[idx] = excl; }
        int total = buf[1023];
        __syncthreads();            // all reads of s_carry/buf done
        if (tid == 0) s_carry += total;
        __syncthreads();
    }
    if (tid == 0) row_start[NN] = s_carry;   // == NE
}

// ---------------------------------------------------------------------------
// CSR build, step 3: reorder edges by dst into packed (src, weight) int2.
// One 8B store per edge; positions for the same dst are contiguous.
// ---------------------------------------------------------------------------
__global__ void reorder_kernel(const int* __restrict__ src,
                               const int* __restrict__ dst,
                               const float* __restrict__ w,
                               int* __restrict__ cursor,
                               int2* __restrict__ e_sw) {
    int e = blockIdx.x * blockDim.x + threadIdx.x;
    if (e >= NE) return;
    int p = atomicAdd(&cursor[dst[e]], 1);
    e_sw[p] = make_int2(src[e], __float_as_int(w[e]));
}

// ---------------------------------------------------------------------------
// Gather: agg[n][:] = sum_{e in-edges of n} w_e * h[src_e][:]
// One wave per node, lane = column. h rows are coalesced 256B reads,
// L2/L3-resident (h = 12.8 MB). No atomics, no memset needed.
// ---------------------------------------------------------------------------
__global__ void gather_kernel(const float* __restrict__ h,
                              const int* __restrict__ row_start,
                              const int2* __restrict__ e_sw,
                              float* __restrict__ agg) {
    int wid = (blockIdx.x * blockDim.x + threadIdx.x) >> 6;
    if (wid >= NN) return;
    int lane = threadIdx.x & 63;
    int beg = row_start[wid];
    int end = row_start[wid + 1];
    float acc = 0.0f;
    for (int i = beg; i < end; ++i) {
        int2 sw = e_sw[i];
        acc += __int_as_float(sw.y) * h[(size_t)sw.x * DD + lane];
    }
    agg[(size_t)wid * DD + lane] = acc;
}

// ---------------------------------------------------------------------------
// Dense update: out = agg @ Wrel + b + h @ Wroot   (+ tanh on last layer)
// Safe for out == h (in-place): each block stages its 16 h-rows into LDS
// before writing those same rows; no cross-block row sharing.
// NOTE: h/out deliberately NOT __restrict__ (they may alias).
// ---------------------------------------------------------------------------
template<bool LAST>
__global__ void update_kernel(const float* __restrict__ agg,
                              const float* h,
                              const float* __restrict__ Wrel,
                              const float* __restrict__ Wroot,
                              const float* __restrict__ b,
                              float* out) {
    constexpr int ROWS = 16;
    __shared__ float sWrel[DD][DD];
    __shared__ float sWroot[DD][DD];
    __shared__ float sAgg[ROWS][DD];
    __shared__ float sH[ROWS][DD];

    const int tid = threadIdx.x;
    for (int i = tid; i < DD * DD / 4; i += blockDim.x) {
        reinterpret_cast<float4*>(&sWrel[0][0])[i]  = reinterpret_cast<const float4*>(Wrel)[i];
        reinterpret_cast<float4*>(&sWroot[0][0])[i] = reinterpret_cast<const float4*>(Wroot)[i];
    }
    const int row0 = blockIdx.x * ROWS;
    for (int i = tid; i < ROWS * DD / 4; i += blockDim.x) {
        int r = i >> 4;
        int c = i & 15;
        int gr = row0 + r;
        if (gr < NN) {
            reinterpret_cast<float4*>(&sAgg[r][0])[c] =
                reinterpret_cast<const float4*>(agg + (size_t)gr * DD)[c];
            reinterpret_cast<float4*>(&sH[r][0])[c] =
                reinterpret_cast<const float4*>(h + (size_t)gr * DD)[c];
        }
    }
    __syncthreads();

    const int d  = tid & 63;
    const int rg = tid >> 6;
    const float bias = b[d];
    #pragma unroll
    for (int rr = 0; rr < 4; ++rr) {
        int r  = rg * 4 + rr;
        int gr = row0 + r;
        if (gr >= NN) continue;
        float acc = bias;
        #pragma unroll
        for (int k = 0; k < DD; ++k) {
            acc += sAgg[r][k] * sWrel[k][d] + sH[r][k] * sWroot[k][d];
        }
        if (LAST) acc = tanhf(acc);
        out[(size_t)gr * DD + d] = acc;
    }
}

extern "C" void kernel_launch(void* const* d_in, const int* in_sizes, int n_in,
                              void* d_out, int out_size, void* d_ws, size_t ws_size,
                              hipStream_t stream) {
    const float* x     = (const float*)d_in[0];
    const int*   ei    = (const int*)d_in[1];
    const float* ew    = (const float*)d_in[2];
    const float* Wrel  = (const float*)d_in[3];
    const float* brel  = (const float*)d_in[4];
    const float* Wroot = (const float*)d_in[5];
    float* out = (float*)d_out;

    // Workspace layout (total ~32.4 MB, fits proven >= 38.4 MB):
    float* agg       = (float*)d_ws;                   // NN*DD f32   (12.8 MB)
    float* hbuf      = agg + (size_t)NN * DD;          // NN*DD f32   (12.8 MB)
    int2*  e_sw      = (int2*)(hbuf + (size_t)NN * DD);// NE int2     ( 6.4 MB)
    int*   row_start = (int*)(e_sw + NE);              // NN+1 ints
    int*   cursor    = row_start + NN + 1;             // NN ints

    const int* src = ei;            // edge_index[0]
    const int* dst = ei + NE;       // edge_index[1]

    const int eblocks = (NE + 255) / 256;              // 3125
    const int gblocks = (NN * 64 + 255) / 256;         // 12500 (1 wave/node)
    const int ublocks = (NN + 15) / 16;                // 3125

    // ---- CSR build (amortized over the 3 layers) ----
    hipMemsetAsync(cursor, 0, (size_t)NN * sizeof(int), stream);
    hist_kernel<<<eblocks, 256, 0, stream>>>(dst, cursor);
    scan_kernel<<<1, 1024, 0, stream>>>(cursor, row_start);
    reorder_kernel<<<eblocks, 256, 0, stream>>>(src, dst, ew, cursor, e_sw);

    // ---- 3 layers: gather (no atomics) + dense update ----
    const float* hcur = x;
    for (int l = 0; l < NL; ++l) {
        gather_kernel<<<gblocks, 256, 0, stream>>>(hcur, row_start, e_sw, agg);
        const float* Wr = Wrel  + (size_t)l * DD * DD;
        const float* Wo = Wroot + (size_t)l * DD * DD;
        const float* bb = brel  + (size_t)l * DD;
        if (l == NL - 1) {
            update_kernel<true><<<ublocks, 256, 0, stream>>>(agg, hcur, Wr, Wo, bb, out);
        } else {
            // l0: x -> hbuf ; l1: hbuf -> hbuf (in-place, safe per-block staging)
            update_kernel<false><<<ublocks, 256, 0, stream>>>(agg, hcur, Wr, Wo, bb, hbuf);
            hcur = hbuf;
        }
    }
}

// Round 6
// 497.921 us; speedup vs baseline: 4.5131x; 1.2180x over previous
//
#include <hip/hip_runtime.h>
#include <hip/hip_bf16.h>

#define NN 50000
#define NE 800000
#define DD 64
#define NL 3

// ---------------------------------------------------------------------------
// CSR build, step 1: in-degree histogram into deg[].
// ---------------------------------------------------------------------------
__global__ void hist_kernel(const int* __restrict__ dst, int* __restrict__ deg) {
    int e = blockIdx.x * blockDim.x + threadIdx.x;
    if (e >= NE) return;
    atomicAdd(&deg[dst[e]], 1);
}

// ---------------------------------------------------------------------------
// CSR build, step 2: segment allocation WITHOUT an ordered prefix scan.
// Order of segments is irrelevant (gather just needs disjoint ranges), so:
// wave-level inclusive scan of deg via __shfl_up, one atomicAdd on a global
// counter per wave (782 total), broadcast base back. Replaces the 94us
// single-block scan with a ~5us full-grid kernel.
// ---------------------------------------------------------------------------
__global__ void alloc_kernel(const int* __restrict__ deg,
                             int* __restrict__ row_start,
                             int* __restrict__ cursor,
                             int* __restrict__ counter) {
    int n = blockIdx.x * blockDim.x + threadIdx.x;
    int lane = threadIdx.x & 63;
    int d = (n < NN) ? deg[n] : 0;
    int s = d;                               // inclusive scan within wave
    #pragma unroll
    for (int off = 1; off < 64; off <<= 1) {
        int t = __shfl_up(s, off);
        if (lane >= off) s += t;
    }
    int total = __shfl(s, 63);
    int base = 0;
    if (lane == 63) base = atomicAdd(counter, total);
    base = __shfl(base, 63);
    int my = base + s - d;                   // exclusive position
    if (n < NN) { row_start[n] = my; cursor[n] = my; }
}

// ---------------------------------------------------------------------------
// CSR build, step 3: reorder edges by dst into packed (src, weight) int2.
// ---------------------------------------------------------------------------
__global__ void reorder_kernel(const int* __restrict__ src,
                               const int* __restrict__ dst,
                               const float* __restrict__ w,
                               int* __restrict__ cursor,
                               int2* __restrict__ e_sw) {
    int e = blockIdx.x * blockDim.x + threadIdx.x;
    if (e >= NE) return;
    int p = atomicAdd(&cursor[dst[e]], 1);
    e_sw[p] = make_int2(src[e], __float_as_int(w[e]));
}

// ---------------------------------------------------------------------------
// Gather: agg[n][:] = sum_{in-edges e of n} w_e * h[src_e][:]
// One wave per node, lane = column. Unroll-by-4 with independent accumulators
// so 4 h-row loads are in flight (breaks the serial dependent chain).
// ---------------------------------------------------------------------------
__global__ void gather_kernel(const float* __restrict__ h,
                              const int* __restrict__ row_start,
                              const int* __restrict__ deg,
                              const int2* __restrict__ e_sw,
                              float* __restrict__ agg) {
    int wid = (blockIdx.x * blockDim.x + threadIdx.x) >> 6;
    if (wid >= NN) return;
    int lane = threadIdx.x & 63;
    int beg = row_start[wid];
    int end = beg + deg[wid];
    float a0 = 0.f, a1 = 0.f, a2 = 0.f, a3 = 0.f;
    int i = beg;
    for (; i + 4 <= end; i += 4) {
        int2 e0 = e_sw[i+0];
        int2 e1 = e_sw[i+1];
        int2 e2 = e_sw[i+2];
        int2 e3 = e_sw[i+3];
        a0 += __int_as_float(e0.y) * h[(size_t)e0.x * DD + lane];
        a1 += __int_as_float(e1.y) * h[(size_t)e1.x * DD + lane];
        a2 += __int_as_float(e2.y) * h[(size_t)e2.x * DD + lane];
        a3 += __int_as_float(e3.y) * h[(size_t)e3.x * DD + lane];
    }
    for (; i < end; ++i) {
        int2 e = e_sw[i];
        a0 += __int_as_float(e.y) * h[(size_t)e.x * DD + lane];
    }
    agg[(size_t)wid * DD + lane] = (a0 + a1) + (a2 + a3);
}

// ---------------------------------------------------------------------------
// Dense update: out = agg @ Wrel + b + h @ Wroot   (+ tanh on last layer)
// No LDS. Lane = output column d. Each wave owns 8 rows (uniform indices via
// readfirstlane -> agg/h row reads become SCALAR loads through the constant
// cache, operand of v_fmac directly). W columns (64x2 floats) live in VGPRs,
// loaded coalesced from global (L1-resident: both W = 32KB), reused across
// the 8 rows. In-place safe: row r is read only by the wave that writes it.
// ---------------------------------------------------------------------------
template<bool LAST>
__global__ void __launch_bounds__(256)
update_kernel(const float* agg, const float* h,
              const float* __restrict__ Wrel, const float* __restrict__ Wroot,
              const float* __restrict__ b, float* out) {
    constexpr int RPW = 8;                    // rows per wave
    const int tid  = threadIdx.x;
    const int lane = tid & 63;                // output column
    const int wv   = __builtin_amdgcn_readfirstlane(tid >> 6);  // uniform 0..3
    const int r0   = blockIdx.x * (4 * RPW) + wv * RPW;         // uniform

    // W columns into registers (static indexing -> stays in VGPRs)
    float w1[DD], w2[DD];
    #pragma unroll
    for (int k = 0; k < DD; ++k) {
        w1[k] = Wrel[k * DD + lane];
        w2[k] = Wroot[k * DD + lane];
    }
    const float bias = b[lane];

    #pragma unroll
    for (int rr = 0; rr < RPW; ++rr) {
        int r = r0 + rr;                      // uniform
        if (r >= NN) break;                   // uniform branch
        const float* ap = agg + (size_t)r * DD;   // uniform pointer -> s_load
        const float* hp = h   + (size_t)r * DD;
        float acc = bias;
        #pragma unroll
        for (int k = 0; k < DD; ++k) {
            acc += ap[k] * w1[k] + hp[k] * w2[k];
        }
        if (LAST) acc = tanhf(acc);
        out[(size_t)r * DD + lane] = acc;
    }
}

extern "C" void kernel_launch(void* const* d_in, const int* in_sizes, int n_in,
                              void* d_out, int out_size, void* d_ws, size_t ws_size,
                              hipStream_t stream) {
    const float* x     = (const float*)d_in[0];
    const int*   ei    = (const int*)d_in[1];
    const float* ew    = (const float*)d_in[2];
    const float* Wrel  = (const float*)d_in[3];
    const float* brel  = (const float*)d_in[4];
    const float* Wroot = (const float*)d_in[5];
    float* out = (float*)d_out;

    // Workspace (~32.6 MB)
    float* agg       = (float*)d_ws;                    // NN*DD f32
    float* hbuf      = agg + (size_t)NN * DD;           // NN*DD f32
    int2*  e_sw      = (int2*)(hbuf + (size_t)NN * DD); // NE int2
    int*   row_start = (int*)(e_sw + NE);               // NN
    int*   cursor    = row_start + NN;                  // NN
    int*   deg       = cursor + NN;                     // NN
    int*   counter   = deg + NN;                        // 1

    const int* src = ei;            // edge_index[0]
    const int* dst = ei + NE;       // edge_index[1]

    const int eblocks = (NE + 255) / 256;               // 3125
    const int ablocks = (NN + 255) / 256;               // 196
    const int gblocks = (NN * 64 + 255) / 256;          // 12500 (1 wave/node)
    const int ublocks = (NN + 31) / 32;                 // 1563 (32 rows/block)

    // ---- CSR build (no ordered scan needed) ----
    hipMemsetAsync(deg, 0, (size_t)(NN + 1) * sizeof(int), stream); // deg + counter
    hist_kernel<<<eblocks, 256, 0, stream>>>(dst, deg);
    alloc_kernel<<<ablocks, 256, 0, stream>>>(deg, row_start, cursor, counter);
    reorder_kernel<<<eblocks, 256, 0, stream>>>(src, dst, ew, cursor, e_sw);

    // ---- 3 layers: gather + dense update ----
    const float* hcur = x;
    for (int l = 0; l < NL; ++l) {
        gather_kernel<<<gblocks, 256, 0, stream>>>(hcur, row_start, deg, e_sw, agg);
        const float* Wr = Wrel  + (size_t)l * DD * DD;
        const float* Wo = Wroot + (size_t)l * DD * DD;
        const float* bb = brel  + (size_t)l * DD;
        if (l == NL - 1) {
            update_kernel<true><<<ublocks, 256, 0, stream>>>(agg, hcur, Wr, Wo, bb, out);
        } else {
            // l0: x -> hbuf ; l1: hbuf -> hbuf (in-place safe)
            update_kernel<false><<<ublocks, 256, 0, stream>>>(agg, hcur, Wr, Wo, bb, hbuf);
            hcur = hbuf;
        }
    }
}

// Round 7
// 361.162 us; speedup vs baseline: 6.2220x; 1.3787x over previous
//
#include <hip/hip_runtime.h>
#include <hip/hip_bf16.h>

#define NN 50000
#define NE 800000
#define DD 64
#define NL 3

__device__ __forceinline__ int rlanei(int v, int l) {
    return __builtin_amdgcn_readlane(v, l);
}
__device__ __forceinline__ float rlane(float v, int l) {
    return __int_as_float(__builtin_amdgcn_readlane(__float_as_int(v), l));
}

// ---------------------------------------------------------------------------
// CSR build, step 1: in-degree histogram into deg[].
// ---------------------------------------------------------------------------
__global__ void hist_kernel(const int* __restrict__ dst, int* __restrict__ deg) {
    int e = blockIdx.x * blockDim.x + threadIdx.x;
    if (e >= NE) return;
    atomicAdd(&deg[dst[e]], 1);
}

// ---------------------------------------------------------------------------
// CSR build, step 2: unordered segment allocation (order irrelevant for a
// sum): wave-level __shfl_up scan + one atomicAdd per wave on a counter.
// ---------------------------------------------------------------------------
__global__ void alloc_kernel(const int* __restrict__ deg,
                             int* __restrict__ row_start,
                             int* __restrict__ cursor,
                             int* __restrict__ counter) {
    int n = blockIdx.x * blockDim.x + threadIdx.x;
    int lane = threadIdx.x & 63;
    int d = (n < NN) ? deg[n] : 0;
    int s = d;
    #pragma unroll
    for (int off = 1; off < 64; off <<= 1) {
        int t = __shfl_up(s, off);
        if (lane >= off) s += t;
    }
    int total = __shfl(s, 63);
    int base = 0;
    if (lane == 63) base = atomicAdd(counter, total);
    base = __shfl(base, 63);
    int my = base + s - d;
    if (n < NN) { row_start[n] = my; cursor[n] = my; }
}

// ---------------------------------------------------------------------------
// CSR build, step 3: reorder edges by dst into packed (src, weight) int2.
// ---------------------------------------------------------------------------
__global__ void reorder_kernel(const int* __restrict__ src,
                               const int* __restrict__ dst,
                               const float* __restrict__ w,
                               int* __restrict__ cursor,
                               int2* __restrict__ e_sw) {
    int e = blockIdx.x * blockDim.x + threadIdx.x;
    if (e >= NE) return;
    int p = atomicAdd(&cursor[dst[e]], 1);
    e_sw[p] = make_int2(src[e], __float_as_int(w[e]));
}

// ---------------------------------------------------------------------------
// Fused layer: per node n (one wave each, grid-stride):
//   agg[lane] = sum_e w_e * h[src_e][lane]        (gather, coalesced row reads)
//   out[n][lane] = b[lane] + sum_k agg[k]*Wrel[k][lane] + h[n][k]*Wroot[k][lane]
// Dense part uses v_readlane broadcasts (agg/h live across the wave's lanes in
// exactly the needed layout) against W columns held in 128 statically-indexed
// VGPRs, amortized over ~16 nodes/wave. Edge (src,w) metadata: one coalesced
// int2 load per 64-edge chunk, then per-edge readlane. No LDS, no agg buffer.
// h (read, incl. random rows) and hout (write) are distinct buffers.
// ---------------------------------------------------------------------------
template<bool LAST>
__global__ void __launch_bounds__(256, 3)
fused_kernel(const float* __restrict__ h,
             const int* __restrict__ row_start,
             const int* __restrict__ deg,
             const int2* __restrict__ e_sw,
             const float* __restrict__ Wrel,
             const float* __restrict__ Wroot,
             const float* __restrict__ b,
             float* __restrict__ hout) {
    const int lane   = threadIdx.x & 63;
    const int wgid   = __builtin_amdgcn_readfirstlane((int)((blockIdx.x * blockDim.x + threadIdx.x) >> 6));
    const int nwaves = (gridDim.x * blockDim.x) >> 6;

    // W columns for this lane -> VGPRs (static indexing via full unroll)
    float w1[DD], w2[DD];
    #pragma unroll
    for (int k = 0; k < DD; ++k) {
        w1[k] = Wrel[k * DD + lane];
        w2[k] = Wroot[k * DD + lane];
    }
    const float bias = b[lane];

    for (int n = wgid; n < NN; n += nwaves) {
        const int beg = row_start[n];
        const int dg  = deg[n];
        const int end = beg + dg;

        // ---- gather ----
        float g0 = 0.f, g1 = 0.f, g2 = 0.f, g3 = 0.f;
        for (int i = beg; i < end; i += 64) {
            int cnt = min(64, end - i);
            int2 e = make_int2(0, 0);
            if (i + lane < end) e = e_sw[i + lane];
            int vs = e.x, vw = e.y;
            int j = 0;
            for (; j + 4 <= cnt; j += 4) {
                int   s0 = rlanei(vs, j+0); float f0 = __int_as_float(rlanei(vw, j+0));
                int   s1 = rlanei(vs, j+1); float f1 = __int_as_float(rlanei(vw, j+1));
                int   s2 = rlanei(vs, j+2); float f2 = __int_as_float(rlanei(vw, j+2));
                int   s3 = rlanei(vs, j+3); float f3 = __int_as_float(rlanei(vw, j+3));
                g0 += f0 * h[(size_t)s0 * DD + lane];
                g1 += f1 * h[(size_t)s1 * DD + lane];
                g2 += f2 * h[(size_t)s2 * DD + lane];
                g3 += f3 * h[(size_t)s3 * DD + lane];
            }
            for (; j < cnt; ++j) {
                int s0 = rlanei(vs, j); float f0 = __int_as_float(rlanei(vw, j));
                g0 += f0 * h[(size_t)s0 * DD + lane];
            }
        }
        const float vagg = (g0 + g1) + (g2 + g3);
        const float vh   = h[(size_t)n * DD + lane];

        // ---- dense: readlane broadcasts x W-in-VGPR ----
        float a0 = bias, a1 = 0.f, a2 = 0.f, a3 = 0.f;
        #pragma unroll
        for (int k = 0; k < DD; k += 2) {
            float sa0 = rlane(vagg, k),     sh0 = rlane(vh, k);
            float sa1 = rlane(vagg, k + 1), sh1 = rlane(vh, k + 1);
            a0 += sa0 * w1[k];
            a1 += sh0 * w2[k];
            a2 += sa1 * w1[k + 1];
            a3 += sh1 * w2[k + 1];
        }
        float r = (a0 + a1) + (a2 + a3);
        if (LAST) r = tanhf(r);
        hout[(size_t)n * DD + lane] = r;
    }
}

extern "C" void kernel_launch(void* const* d_in, const int* in_sizes, int n_in,
                              void* d_out, int out_size, void* d_ws, size_t ws_size,
                              hipStream_t stream) {
    const float* x     = (const float*)d_in[0];
    const int*   ei    = (const int*)d_in[1];
    const float* ew    = (const float*)d_in[2];
    const float* Wrel  = (const float*)d_in[3];
    const float* brel  = (const float*)d_in[4];
    const float* Wroot = (const float*)d_in[5];
    float* out = (float*)d_out;

    // Workspace (~32.6 MB): two h buffers (ping-pong; gather reads random rows
    // so layers can NOT run in-place), edge list, CSR meta.
    float* hA        = (float*)d_ws;                    // NN*DD f32
    float* hB        = hA + (size_t)NN * DD;            // NN*DD f32
    int2*  e_sw      = (int2*)(hB + (size_t)NN * DD);   // NE int2
    int*   row_start = (int*)(e_sw + NE);               // NN
    int*   cursor    = row_start + NN;                  // NN
    int*   deg       = cursor + NN;                     // NN
    int*   counter   = deg + NN;                        // 1

    const int* src = ei;            // edge_index[0]
    const int* dst = ei + NE;       // edge_index[1]

    const int eblocks = (NE + 255) / 256;               // 3125
    const int ablocks = (NN + 255) / 256;               // 196
    const int fblocks = 768;                            // 3072 waves, ~16 nodes/wave

    // ---- CSR build ----
    hipMemsetAsync(deg, 0, (size_t)(NN + 1) * sizeof(int), stream); // deg + counter
    hist_kernel<<<eblocks, 256, 0, stream>>>(dst, deg);
    alloc_kernel<<<ablocks, 256, 0, stream>>>(deg, row_start, cursor, counter);
    reorder_kernel<<<eblocks, 256, 0, stream>>>(src, dst, ew, cursor, e_sw);

    // ---- 3 fused layers: x -> hA -> hB -> out ----
    fused_kernel<false><<<fblocks, 256, 0, stream>>>(x,  row_start, deg, e_sw, Wrel,            Wroot,            brel,          hA);
    fused_kernel<false><<<fblocks, 256, 0, stream>>>(hA, row_start, deg, e_sw, Wrel + DD*DD,    Wroot + DD*DD,    brel + DD,     hB);
    fused_kernel<true ><<<fblocks, 256, 0, stream>>>(hB, row_start, deg, e_sw, Wrel + 2*DD*DD,  Wroot + 2*DD*DD,  brel + 2*DD,   out);
}